// Round 1
// baseline (244.527 us; speedup 1.0000x reference)
//
#include <hip/hip_runtime.h>

// Problem constants (fixed by the reference).
#define Bc   8
#define Cc   16
#define Hc   256
#define Wc   256
#define HWc  (Hc * Wc)          // 65536
#define HIDc 32
#define Npix (Bc * HWc)         // 524288 pixels
#define FUSED_ELEMS (Bc * Cc * HWc)   // 8388608
#define PREF_ELEMS  (Cc * 2)          // 32

__global__ __launch_bounds__(256) void CategoryAwareGate_kernel(
    const float* __restrict__ swin,   // (B,C,H,W)
    const float* __restrict__ gru,    // (B,C,H,W)
    const float* __restrict__ W1,     // (C,HID,2)
    const float* __restrict__ b1,     // (C,HID)
    const float* __restrict__ W2,     // (C,2,HID)
    const float* __restrict__ b2,     // (C,2)
    const float* __restrict__ pref,   // (C,2)
    float* __restrict__ out)          // fused | pref | dw
{
    const int n    = blockIdx.x * 256 + threadIdx.x;  // pixel id in [0, Npix)
    const int bidx = n >> 16;                          // n / (H*W)
    const int hw   = n & (HWc - 1);

    const float* sptr = swin + (size_t)bidx * (Cc * HWc) + hw;
    const float* gptr = gru  + (size_t)bidx * (Cc * HWc) + hw;

    // Load the 16 class logits for this pixel (lane-coalesced, stride HW).
    float sl[Cc], gl[Cc];
#pragma unroll
    for (int c = 0; c < Cc; ++c) {
        sl[c] = sptr[c * HWc];
        gl[c] = gptr[c * HWc];
    }

    // Class-dim softmax prep (max + denom), matching jax.nn.softmax numerics.
    float ms = sl[0], mg = gl[0];
#pragma unroll
    for (int c = 1; c < Cc; ++c) {
        ms = fmaxf(ms, sl[c]);
        mg = fmaxf(mg, gl[c]);
    }
    float ss = 0.f, sg = 0.f;
#pragma unroll
    for (int c = 0; c < Cc; ++c) {
        ss += __expf(sl[c] - ms);
        sg += __expf(gl[c] - mg);
    }
    const float invs = __builtin_amdgcn_rcpf(ss);
    const float invg = __builtin_amdgcn_rcpf(sg);

    float* fop = out + (size_t)bidx * (Cc * HWc) + hw;          // fused output base
    float* dwp = out + (size_t)FUSED_ELEMS + PREF_ELEMS
                     + (size_t)n * (Cc * 2);                    // dw for this pixel

    // Per-class gate MLP + 2-way softmax + fusion.
    for (int c = 0; c < Cc; ++c) {
        const float sp = __expf(sl[c] - ms) * invs;
        const float gp = __expf(gl[c] - mg) * invg;

        // Uniform (scalar) weight pointers for this class.
        const float* w1c = W1 + c * (HIDc * 2);
        const float* b1c = b1 + c * HIDc;
        const float* w2c = W2 + c * (2 * HIDc);

        float a0 = b2[c * 2 + 0];
        float a1 = b2[c * 2 + 1];
#pragma unroll
        for (int k = 0; k < HIDc; ++k) {
            float h = fmaf(w1c[k * 2 + 0], sp,
                      fmaf(w1c[k * 2 + 1], gp, b1c[k]));
            h = fmaxf(h, 0.f);
            a0 = fmaf(w2c[k], h, a0);
            a1 = fmaf(w2c[HIDc + k], h, a1);
        }

        // softmax over the 2 experts
        const float m  = fmaxf(a0, a1);
        const float e0 = __expf(a0 - m);
        const float e1 = __expf(a1 - m);
        const float iv = __builtin_amdgcn_rcpf(e0 + e1);
        const float w0 = e0 * iv;
        const float w1 = e1 * iv;

        fop[c * HWc] = fmaf(w0, sl[c], w1 * gl[c]);
        reinterpret_cast<float2*>(dwp)[c] = make_float2(w0, w1);
    }

    // expert_preferences passthrough (32 floats) by block 0.
    if (blockIdx.x == 0 && threadIdx.x < PREF_ELEMS) {
        out[(size_t)FUSED_ELEMS + threadIdx.x] = pref[threadIdx.x];
    }
}

extern "C" void kernel_launch(void* const* d_in, const int* in_sizes, int n_in,
                              void* d_out, int out_size, void* d_ws, size_t ws_size,
                              hipStream_t stream) {
    const float* swin = (const float*)d_in[0];
    const float* gru  = (const float*)d_in[1];
    const float* W1   = (const float*)d_in[2];
    const float* b1   = (const float*)d_in[3];
    const float* W2   = (const float*)d_in[4];
    const float* b2   = (const float*)d_in[5];
    const float* pref = (const float*)d_in[6];
    float* out = (float*)d_out;

    dim3 grid(Npix / 256);
    dim3 block(256);
    hipLaunchKernelGGL(CategoryAwareGate_kernel, grid, block, 0, stream,
                       swin, gru, W1, b1, W2, b2, pref, out);
}

// Round 2
// 211.874 us; speedup vs baseline: 1.1541x; 1.1541x over previous
//
#include <hip/hip_runtime.h>

// Problem constants (fixed by the reference).
#define Bc   8
#define Cc   16
#define Hc   256
#define Wc   256
#define HWc  (Hc * Wc)          // 65536
#define HIDc 32
#define Npix (Bc * HWc)         // 524288 pixels
#define FUSED_ELEMS (Bc * Cc * HWc)   // 8388608
#define PREF_ELEMS  (Cc * 2)          // 32
#define TPB  256
#define PAD  33                 // LDS row stride (dwords) — bank = (tid+e)%32, conflict-free

__global__ __launch_bounds__(TPB) void CategoryAwareGate_kernel(
    const float* __restrict__ swin,   // (B,C,H,W)
    const float* __restrict__ gru,    // (B,C,H,W)
    const float* __restrict__ W1,     // (C,HID,2)
    const float* __restrict__ b1,     // (C,HID)
    const float* __restrict__ W2,     // (C,2,HID)
    const float* __restrict__ b2,     // (C,2)
    const float* __restrict__ pref,   // (C,2)
    float* __restrict__ out)          // fused | pref | dw
{
    // dw staging: 256 pixels x 32 floats, padded to 33 to kill bank conflicts.
    __shared__ float dwbuf[TPB * PAD];

    const int tid  = threadIdx.x;
    const int n    = blockIdx.x * TPB + tid;   // pixel id
    const int bidx = n >> 16;                  // n / (H*W)
    const int hw   = n & (HWc - 1);

    const float* sptr = swin + (size_t)bidx * (Cc * HWc) + hw;
    const float* gptr = gru  + (size_t)bidx * (Cc * HWc) + hw;

    // Load 16 class logits per expert (lane-coalesced, stride HW between classes).
    float sl[Cc], gl[Cc];
#pragma unroll
    for (int c = 0; c < Cc; ++c) {
        sl[c] = sptr[c * HWc];
        gl[c] = gptr[c * HWc];
    }

    // Class-dim softmax: max, then cache the exp numerators (reused below).
    float ms = sl[0], mg = gl[0];
#pragma unroll
    for (int c = 1; c < Cc; ++c) {
        ms = fmaxf(ms, sl[c]);
        mg = fmaxf(mg, gl[c]);
    }
    float es[Cc], eg[Cc];
    float ss = 0.f, sg = 0.f;
#pragma unroll
    for (int c = 0; c < Cc; ++c) {
        es[c] = __expf(sl[c] - ms);  ss += es[c];
        eg[c] = __expf(gl[c] - mg);  sg += eg[c];
    }
    const float invs = __builtin_amdgcn_rcpf(ss);
    const float invg = __builtin_amdgcn_rcpf(sg);

    float* fop = out + (size_t)bidx * (Cc * HWc) + hw;   // fused output base

    // Per-class gate MLP + 2-way softmax + fusion.
#pragma unroll
    for (int c = 0; c < Cc; ++c) {
        const float sp = es[c] * invs;
        const float gp = eg[c] * invg;

        const float* w1c = W1 + c * (HIDc * 2);   // uniform -> scalar loads
        const float* b1c = b1 + c * HIDc;
        const float* w2c = W2 + c * (2 * HIDc);

        float a0 = b2[c * 2 + 0];
        float a1 = b2[c * 2 + 1];
#pragma unroll
        for (int k = 0; k < HIDc; ++k) {
            float h = fmaf(w1c[k * 2 + 0], sp,
                      fmaf(w1c[k * 2 + 1], gp, b1c[k]));
            h = fmaxf(h, 0.f);
            a0 = fmaf(w2c[k], h, a0);
            a1 = fmaf(w2c[HIDc + k], h, a1);
        }

        const float m  = fmaxf(a0, a1);
        const float e0 = __expf(a0 - m);
        const float e1 = __expf(a1 - m);
        const float iv = __builtin_amdgcn_rcpf(e0 + e1);
        const float w0 = e0 * iv;
        const float w1 = e1 * iv;

        fop[c * HWc] = fmaf(w0, sl[c], w1 * gl[c]);   // coalesced (stride 1 over lanes)

        dwbuf[tid * PAD + 2 * c]     = w0;            // bank (tid + 2c) % 32 — conflict-free
        dwbuf[tid * PAD + 2 * c + 1] = w1;
    }

    __syncthreads();

    // Drain dw coalesced: this block owns out[dwbase .. dwbase + 8192).
    const size_t dwbase = (size_t)FUSED_ELEMS + PREF_ELEMS
                        + (size_t)blockIdx.x * (TPB * Cc * 2);
#pragma unroll
    for (int j = 0; j < Cc * 2; ++j) {
        const int i = j * TPB + tid;                  // flat index in block's dw region
        out[dwbase + i] = dwbuf[(i >> 5) * PAD + (i & 31)];  // bank (p+e)%32 — conflict-free
    }

    // expert_preferences passthrough (32 floats) by block 0.
    if (blockIdx.x == 0 && tid < PREF_ELEMS) {
        out[(size_t)FUSED_ELEMS + tid] = pref[tid];
    }
}

extern "C" void kernel_launch(void* const* d_in, const int* in_sizes, int n_in,
                              void* d_out, int out_size, void* d_ws, size_t ws_size,
                              hipStream_t stream) {
    const float* swin = (const float*)d_in[0];
    const float* gru  = (const float*)d_in[1];
    const float* W1   = (const float*)d_in[2];
    const float* b1   = (const float*)d_in[3];
    const float* W2   = (const float*)d_in[4];
    const float* b2   = (const float*)d_in[5];
    const float* pref = (const float*)d_in[6];
    float* out = (float*)d_out;

    dim3 grid(Npix / TPB);
    dim3 block(TPB);
    hipLaunchKernelGGL(CategoryAwareGate_kernel, grid, block, 0, stream,
                       swin, gru, W1, b1, W2, b2, pref, out);
}

// Round 3
// 210.467 us; speedup vs baseline: 1.1618x; 1.0067x over previous
//
#include <hip/hip_runtime.h>

// Problem constants (fixed by the reference).
#define Bc   8
#define Cc   16
#define Hc   256
#define Wc   256
#define HWc  (Hc * Wc)          // 65536
#define HIDc 32
#define Npix (Bc * HWc)         // 524288 pixels
#define FUSED_ELEMS (Bc * Cc * HWc)   // 8388608
#define PREF_ELEMS  (Cc * 2)          // 32
#define TPB  256

// block=256, 4 waves/SIMD: LDS (32 KB) caps us at 4 blocks/CU anyway, so let
// the register allocator use the full 128-VGPR budget and keep the 64-float
// per-pixel state live instead of rematerializing (R2: 52 VGPRs, 2.3x VALU
// inflation).
__global__ __launch_bounds__(TPB, 4) void CategoryAwareGate_kernel(
    const float* __restrict__ swin,   // (B,C,H,W)
    const float* __restrict__ gru,    // (B,C,H,W)
    const float* __restrict__ W1,     // (C,HID,2)
    const float* __restrict__ b1,     // (C,HID)
    const float* __restrict__ W2,     // (C,2,HID)
    const float* __restrict__ b2,     // (C,2)
    const float* __restrict__ pref,   // (C,2)
    float* __restrict__ out)          // fused | pref | dw
{
    // dw staging: 256 pixels x 16 float2, XOR-rotation swizzled -> exactly
    // 32 KB, conflict-free for both the scattered write and the coalesced
    // drain read (4 lanes/bank-pair, uniform).
    __shared__ float2 dwbuf2[TPB * Cc];

    const int tid  = threadIdx.x;
    const int n    = blockIdx.x * TPB + tid;   // pixel id
    const int bidx = n >> 16;                  // n / (H*W)
    const int hw   = n & (HWc - 1);

    const float* sptr = swin + (size_t)bidx * (Cc * HWc) + hw;
    const float* gptr = gru  + (size_t)bidx * (Cc * HWc) + hw;

    // Load 16 class logits per expert (lane-coalesced, stride HW between classes).
    float sl[Cc], gl[Cc];
#pragma unroll
    for (int c = 0; c < Cc; ++c) {
        sl[c] = sptr[c * HWc];
        gl[c] = gptr[c * HWc];
    }

    // Class-dim softmax: max, then cache the exp numerators (reused in MLP).
    float ms = sl[0], mg = gl[0];
#pragma unroll
    for (int c = 1; c < Cc; ++c) {
        ms = fmaxf(ms, sl[c]);
        mg = fmaxf(mg, gl[c]);
    }
    float es[Cc], eg[Cc];
    float ss = 0.f, sg = 0.f;
#pragma unroll
    for (int c = 0; c < Cc; ++c) {
        es[c] = __expf(sl[c] - ms);  ss += es[c];
        eg[c] = __expf(gl[c] - mg);  sg += eg[c];
    }
    const float invs = __builtin_amdgcn_rcpf(ss);
    const float invg = __builtin_amdgcn_rcpf(sg);

    float* fop = out + (size_t)bidx * (Cc * HWc) + hw;   // fused output base

    // Per-class gate MLP + sigmoid gate + fusion.
#pragma unroll
    for (int c = 0; c < Cc; ++c) {
        const float sp = es[c] * invs;
        const float gp = eg[c] * invg;

        const float* w1c = W1 + c * (HIDc * 2);   // uniform -> scalar loads
        const float* b1c = b1 + c * HIDc;
        const float* w2c = W2 + c * (2 * HIDc);

        float a0 = b2[c * 2 + 0];
        float a1 = b2[c * 2 + 1];
#pragma unroll
        for (int k = 0; k < HIDc; ++k) {
            float h = fmaf(w1c[k * 2 + 0], sp,
                      fmaf(w1c[k * 2 + 1], gp, b1c[k]));
            h = fmaxf(h, 0.f);
            a0 = fmaf(w2c[k], h, a0);
            a1 = fmaf(w2c[HIDc + k], h, a1);
        }

        // softmax over 2 == stable sigmoid of the difference (saves one exp)
        const float d = a0 - a1;
        const float t = __expf(-fabsf(d));
        const float r = __builtin_amdgcn_rcpf(1.f + t);  // weight of the larger
        const float w0 = (d >= 0.f) ? r : 1.f - r;
        const float w1 = 1.f - w0;

        fop[c * HWc] = fmaf(w0, sl[c], w1 * gl[c]);      // coalesced store

        dwbuf2[tid * Cc + ((c + tid) & (Cc - 1))] = make_float2(w0, w1);
    }

    __syncthreads();

    // Drain dw coalesced: block owns 4096 float2 = 32 KB of out.
    float2* outv2 = reinterpret_cast<float2*>(
        out + (size_t)FUSED_ELEMS + PREF_ELEMS + (size_t)blockIdx.x * (TPB * Cc * 2));
#pragma unroll
    for (int j = 0; j < Cc; ++j) {
        const int pi = j * TPB + tid;        // pair index in block's dw region
        const int p  = pi >> 4;              // pixel (row in dwbuf2)
        const int pr = pi & (Cc - 1);        // pair-in-pixel
        outv2[pi] = dwbuf2[p * Cc + ((pr + p) & (Cc - 1))];
    }

    // expert_preferences passthrough (32 floats) by block 0.
    if (blockIdx.x == 0 && tid < PREF_ELEMS) {
        out[(size_t)FUSED_ELEMS + tid] = pref[tid];
    }
}

extern "C" void kernel_launch(void* const* d_in, const int* in_sizes, int n_in,
                              void* d_out, int out_size, void* d_ws, size_t ws_size,
                              hipStream_t stream) {
    const float* swin = (const float*)d_in[0];
    const float* gru  = (const float*)d_in[1];
    const float* W1   = (const float*)d_in[2];
    const float* b1   = (const float*)d_in[3];
    const float* W2   = (const float*)d_in[4];
    const float* b2   = (const float*)d_in[5];
    const float* pref = (const float*)d_in[6];
    float* out = (float*)d_out;

    dim3 grid(Npix / TPB);
    dim3 block(TPB);
    hipLaunchKernelGGL(CategoryAwareGate_kernel, grid, block, 0, stream,
                       swin, gru, W1, b1, W2, b2, pref, out);
}

// Round 4
// 201.823 us; speedup vs baseline: 1.2116x; 1.0428x over previous
//
#include <hip/hip_runtime.h>

typedef float v2f __attribute__((ext_vector_type(2)));

// Problem constants (fixed by the reference).
#define Bc   8
#define Cc   16
#define HWc  65536              // 256*256
#define HIDc 32
#define Npix (Bc * HWc)         // 524288 pixels
#define FUSED_ELEMS (Bc * Cc * HWc)   // 8388608
#define PREF_ELEMS  (Cc * 2)          // 32
#define TPB  256
#define WSTRIDE 81                    // float2 slots per class in packed ws
#define PACKED_BYTES (Cc * WSTRIDE * 8)  // 10368 B

// ---------------------------------------------------------------------------
// Prep: reorganize weights into hidden-pair-contiguous float2s so the main
// kernel's uniform loads become s_load_dwordx2/x8 feeding v_pk_fma_f32
// SGPR-pair operands directly. Layout per class (float2 index):
//   [0..15]  w1s pairs  (W1[c][2j][0],  W1[c][2j+1][0])
//   [16..31] w1g pairs  (W1[c][2j][1],  W1[c][2j+1][1])
//   [32..47] b1 pairs   (b1[c][2j],     b1[c][2j+1])
//   [48..63] w2_0 pairs (W2[c][0][2j],  W2[c][0][2j+1])
//   [64..79] w2_1 pairs (W2[c][1][2j],  W2[c][1][2j+1])
//   [80]     b2 pair    (b2[c][0],      b2[c][1])
// ---------------------------------------------------------------------------
__global__ void gate_prep(const float* __restrict__ W1, const float* __restrict__ b1,
                          const float* __restrict__ W2, const float* __restrict__ b2,
                          v2f* __restrict__ ws)
{
    const int c = blockIdx.x;
    const int j = threadIdx.x;
    v2f* wp = ws + c * WSTRIDE;
    if (j < 16) {
        wp[j]      = (v2f){W1[c*64 + 4*j + 0], W1[c*64 + 4*j + 2]};
        wp[16 + j] = (v2f){W1[c*64 + 4*j + 1], W1[c*64 + 4*j + 3]};
        wp[32 + j] = (v2f){b1[c*32 + 2*j],     b1[c*32 + 2*j + 1]};
        wp[48 + j] = (v2f){W2[c*64 + 2*j],     W2[c*64 + 2*j + 1]};
        wp[64 + j] = (v2f){W2[c*64 + 32 + 2*j],W2[c*64 + 32 + 2*j + 1]};
    } else if (j == 16) {
        wp[80] = (v2f){b2[2*c], b2[2*c + 1]};
    }
}

// ---------------------------------------------------------------------------
// Main kernel, packed-fp32 MLP. waves_per_eu(4,4) pins the allocator's
// occupancy target so the 64 live per-pixel floats stay in VGPRs (R3: the
// default 8-wave target gave 60 VGPRs and ~2.3x VALU rematerialization).
// LDS (32 KB) caps blocks/CU at 4-5 anyway.
// ---------------------------------------------------------------------------
__global__ __launch_bounds__(TPB)
__attribute__((amdgpu_waves_per_eu(4, 4)))
void gate_main_packed(
    const float* __restrict__ swin, const float* __restrict__ gru,
    const v2f* __restrict__ wsw, const float* __restrict__ pref,
    float* __restrict__ out)
{
    __shared__ float2 dwbuf2[TPB * Cc];   // 32 KB, XOR-rotation swizzled

    const int tid  = threadIdx.x;
    const int n    = blockIdx.x * TPB + tid;
    const int bidx = n >> 16;
    const int hw   = n & (HWc - 1);

    const float* sptr = swin + (size_t)bidx * (Cc * HWc) + hw;
    const float* gptr = gru  + (size_t)bidx * (Cc * HWc) + hw;

    float sl[Cc], gl[Cc];
#pragma unroll
    for (int c = 0; c < Cc; ++c) {
        sl[c] = sptr[c * HWc];
        gl[c] = gptr[c * HWc];
    }

    float ms = sl[0], mg = gl[0];
#pragma unroll
    for (int c = 1; c < Cc; ++c) {
        ms = fmaxf(ms, sl[c]);
        mg = fmaxf(mg, gl[c]);
    }
    float es[Cc], eg[Cc];
    float ss = 0.f, sg = 0.f;
#pragma unroll
    for (int c = 0; c < Cc; ++c) {
        es[c] = __expf(sl[c] - ms);  ss += es[c];
        eg[c] = __expf(gl[c] - mg);  sg += eg[c];
    }
    const float invs = __builtin_amdgcn_rcpf(ss);
    const float invg = __builtin_amdgcn_rcpf(sg);

    float* fop = out + (size_t)bidx * (Cc * HWc) + hw;

#pragma unroll
    for (int c = 0; c < Cc; ++c) {
        const float sp = es[c] * invs;
        const float gp = eg[c] * invg;
        const v2f spv = {sp, sp};
        const v2f gpv = {gp, gp};

        const v2f* wp = wsw + c * WSTRIDE;

        v2f acc0 = {0.f, 0.f};
        v2f acc1 = {0.f, 0.f};
#pragma unroll
        for (int j = 0; j < HIDc / 2; ++j) {
            v2f h = wp[j] * spv + (wp[16 + j] * gpv + wp[32 + j]);  // pk_fma x2
            h = __builtin_elementwise_max(h, (v2f){0.f, 0.f});       // pk_max
            acc0 = h * wp[48 + j] + acc0;                            // pk_fma
            acc1 = h * wp[64 + j] + acc1;                            // pk_fma
        }
        const v2f b2v = wp[80];
        const float a0 = acc0.x + acc0.y + b2v.x;
        const float a1 = acc1.x + acc1.y + b2v.y;

        // softmax over 2 == stable sigmoid of the difference
        const float d = a0 - a1;
        const float t = __expf(-fabsf(d));
        const float r = __builtin_amdgcn_rcpf(1.f + t);
        const float w0 = (d >= 0.f) ? r : 1.f - r;
        const float w1 = 1.f - w0;

        fop[c * HWc] = fmaf(w0, sl[c], w1 * gl[c]);

        dwbuf2[tid * Cc + ((c + tid) & (Cc - 1))] = make_float2(w0, w1);
    }

    __syncthreads();

    float2* outv2 = reinterpret_cast<float2*>(
        out + (size_t)FUSED_ELEMS + PREF_ELEMS + (size_t)blockIdx.x * (TPB * Cc * 2));
#pragma unroll
    for (int j = 0; j < Cc; ++j) {
        const int pi = j * TPB + tid;
        const int p  = pi >> 4;
        const int pr = pi & (Cc - 1);
        outv2[pi] = dwbuf2[p * Cc + ((pr + p) & (Cc - 1))];
    }

    if (blockIdx.x == 0 && tid < PREF_ELEMS) {
        out[(size_t)FUSED_ELEMS + tid] = pref[tid];
    }
}

// ---------------------------------------------------------------------------
// Fallback (R3 kernel) if ws_size is too small for the packed weights.
// ---------------------------------------------------------------------------
__global__ __launch_bounds__(TPB, 4) void gate_main_scalar(
    const float* __restrict__ swin, const float* __restrict__ gru,
    const float* __restrict__ W1, const float* __restrict__ b1,
    const float* __restrict__ W2, const float* __restrict__ b2,
    const float* __restrict__ pref, float* __restrict__ out)
{
    __shared__ float2 dwbuf2[TPB * Cc];

    const int tid  = threadIdx.x;
    const int n    = blockIdx.x * TPB + tid;
    const int bidx = n >> 16;
    const int hw   = n & (HWc - 1);

    const float* sptr = swin + (size_t)bidx * (Cc * HWc) + hw;
    const float* gptr = gru  + (size_t)bidx * (Cc * HWc) + hw;

    float sl[Cc], gl[Cc];
#pragma unroll
    for (int c = 0; c < Cc; ++c) { sl[c] = sptr[c * HWc]; gl[c] = gptr[c * HWc]; }

    float ms = sl[0], mg = gl[0];
#pragma unroll
    for (int c = 1; c < Cc; ++c) { ms = fmaxf(ms, sl[c]); mg = fmaxf(mg, gl[c]); }
    float es[Cc], eg[Cc];
    float ss = 0.f, sg = 0.f;
#pragma unroll
    for (int c = 0; c < Cc; ++c) {
        es[c] = __expf(sl[c] - ms);  ss += es[c];
        eg[c] = __expf(gl[c] - mg);  sg += eg[c];
    }
    const float invs = __builtin_amdgcn_rcpf(ss);
    const float invg = __builtin_amdgcn_rcpf(sg);

    float* fop = out + (size_t)bidx * (Cc * HWc) + hw;

#pragma unroll
    for (int c = 0; c < Cc; ++c) {
        const float sp = es[c] * invs;
        const float gp = eg[c] * invg;
        const float* w1c = W1 + c * (HIDc * 2);
        const float* b1c = b1 + c * HIDc;
        const float* w2c = W2 + c * (2 * HIDc);

        float a0 = b2[c * 2 + 0];
        float a1 = b2[c * 2 + 1];
#pragma unroll
        for (int k = 0; k < HIDc; ++k) {
            float h = fmaf(w1c[k * 2 + 0], sp, fmaf(w1c[k * 2 + 1], gp, b1c[k]));
            h = fmaxf(h, 0.f);
            a0 = fmaf(w2c[k], h, a0);
            a1 = fmaf(w2c[HIDc + k], h, a1);
        }
        const float d = a0 - a1;
        const float t = __expf(-fabsf(d));
        const float r = __builtin_amdgcn_rcpf(1.f + t);
        const float w0 = (d >= 0.f) ? r : 1.f - r;
        const float w1 = 1.f - w0;

        fop[c * HWc] = fmaf(w0, sl[c], w1 * gl[c]);
        dwbuf2[tid * Cc + ((c + tid) & (Cc - 1))] = make_float2(w0, w1);
    }

    __syncthreads();

    float2* outv2 = reinterpret_cast<float2*>(
        out + (size_t)FUSED_ELEMS + PREF_ELEMS + (size_t)blockIdx.x * (TPB * Cc * 2));
#pragma unroll
    for (int j = 0; j < Cc; ++j) {
        const int pi = j * TPB + tid;
        const int p  = pi >> 4;
        const int pr = pi & (Cc - 1);
        outv2[pi] = dwbuf2[p * Cc + ((pr + p) & (Cc - 1))];
    }

    if (blockIdx.x == 0 && tid < PREF_ELEMS) {
        out[(size_t)FUSED_ELEMS + tid] = pref[tid];
    }
}

extern "C" void kernel_launch(void* const* d_in, const int* in_sizes, int n_in,
                              void* d_out, int out_size, void* d_ws, size_t ws_size,
                              hipStream_t stream) {
    const float* swin = (const float*)d_in[0];
    const float* gru  = (const float*)d_in[1];
    const float* W1   = (const float*)d_in[2];
    const float* b1   = (const float*)d_in[3];
    const float* W2   = (const float*)d_in[4];
    const float* b2   = (const float*)d_in[5];
    const float* pref = (const float*)d_in[6];
    float* out = (float*)d_out;

    dim3 grid(Npix / TPB);
    dim3 block(TPB);

    if (ws_size >= (size_t)PACKED_BYTES) {
        v2f* ws = (v2f*)d_ws;
        hipLaunchKernelGGL(gate_prep, dim3(Cc), dim3(64), 0, stream, W1, b1, W2, b2, ws);
        hipLaunchKernelGGL(gate_main_packed, grid, block, 0, stream,
                           swin, gru, ws, pref, out);
    } else {
        hipLaunchKernelGGL(gate_main_scalar, grid, block, 0, stream,
                           swin, gru, W1, b1, W2, b2, pref, out);
    }
}